// Round 6
// baseline (829.364 us; speedup 1.0000x reference)
//
#include <hip/hip_runtime.h>
#include <hip/hip_bf16.h>
#include <cstddef>

#define GN 50000
#define GE 800000
#define GH 4
#define GD 32
#define SLOPE 0.2f

typedef unsigned short ushort_t;
typedef unsigned int uint_t;
using short8 = __attribute__((ext_vector_type(8))) short;
using float4v = __attribute__((ext_vector_type(4))) float;

__device__ __forceinline__ ushort_t f2bf(float f) {
    union { float f; uint_t u; } v; v.f = f;
    uint_t r = v.u + 0x7fff + ((v.u >> 16) & 1);   // RNE
    return (ushort_t)(r >> 16);
}
__device__ __forceinline__ float bflo(uint_t u) { return __uint_as_float(u << 16); }
__device__ __forceinline__ float bfhi(uint_t u) { return __uint_as_float(u & 0xffff0000u); }

// ---------------- CSR build ----------------
__global__ void k_hist(const int* __restrict__ dst, int* __restrict__ deg, int E) {
    int i = blockIdx.x * 256 + threadIdx.x;
    if (i < E) atomicAdd(&deg[dst[i]], 1);
}

__global__ void k_scan1(const int* __restrict__ deg, int* __restrict__ row_ptr,
                        int* __restrict__ partials, int n) {
    __shared__ int s[256];
    int t = threadIdx.x;
    int i = blockIdx.x * 256 + t;
    int v = (i < n) ? deg[i] : 0;
    s[t] = v;
    __syncthreads();
    for (int off = 1; off < 256; off <<= 1) {
        int add = (t >= off) ? s[t - off] : 0;
        __syncthreads();
        s[t] += add;
        __syncthreads();
    }
    if (i < n) row_ptr[i] = s[t] - v;
    if (t == 255) partials[blockIdx.x] = s[255];
}

__global__ void k_scan2(int* __restrict__ partials, int nb) {
    __shared__ int s[256];
    int t = threadIdx.x;
    int v = (t < nb) ? partials[t] : 0;
    s[t] = v;
    __syncthreads();
    for (int off = 1; off < 256; off <<= 1) {
        int add = (t >= off) ? s[t - off] : 0;
        __syncthreads();
        s[t] += add;
        __syncthreads();
    }
    if (t < nb) partials[t] = s[t] - v;
}

__global__ void k_scan3(int* __restrict__ row_ptr, int* __restrict__ wpos,
                        const int* __restrict__ partials, int n, int E) {
    int i = blockIdx.x * 256 + threadIdx.x;
    if (i < n) {
        int rp = row_ptr[i] + partials[i >> 8];
        row_ptr[i] = rp;
        wpos[i] = rp;
        if (i == 0) row_ptr[n] = E;
    }
}

__global__ void k_fill(const int* __restrict__ src, const int* __restrict__ dst,
                       int* __restrict__ wpos, int2* __restrict__ csr_sd, int E) {
    int i = blockIdx.x * 256 + threadIdx.x;
    if (i < E) {
        int d = dst[i];
        int p = atomicAdd(&wpos[d], 1);
        csr_sd[p] = make_int2(src[i], d);
    }
}

// extract pure src array (coalesced pass; halves agg's index traffic)
__global__ void k_split(const int2* __restrict__ csr_sd, int* __restrict__ csr_src, int E) {
    int i = blockIdx.x * 256 + threadIdx.x;
    if (i < E) csr_src[i] = csr_sd[i].x;
}

// ---------------- weight transpose+convert ----------------
__global__ void k_cvt_w(const float* __restrict__ W0, const float* __restrict__ W1,
                        ushort_t* __restrict__ wbt) {
    int t = blockIdx.x * 256 + threadIdx.x;   // 0..32767
    int m = t >> 14;
    int o = t & 16383;
    int n = o >> 7, k = o & 127;
    const float* W = m ? W1 : W0;
    wbt[t] = f2bf(W[k * 128 + n]);
}

// tiled feat address: featt[(path*8 + ct)*GN + node][16]
__device__ __forceinline__ size_t ftidx(int path, int ct, int node, int col) {
    return (((size_t)(path * 8 + ct)) * GN + node) * 16 + col;
}

// ---------------- MFMA GEMM (fp32 A, layer 1): featt = tiled([A0;A1] @ W) ----------------
__global__ __launch_bounds__(256) void gemm_mfma32(const float* __restrict__ A0,
                                                   const float* __restrict__ A1,
                                                   const ushort_t* __restrict__ WbT,
                                                   ushort_t* __restrict__ featt, int M) {
    __shared__ ushort_t Bs[128][136];
    int tid = threadIdx.x;
    for (int i = tid; i < 128 * 16; i += 256) {
        int n = i >> 4;
        int kc = (i & 15) << 3;
        *(short8*)&Bs[n][kc] = *(const short8*)&WbT[n * 128 + kc];
    }
    __syncthreads();
    int wid = tid >> 6, lane = tid & 63;
    int r0 = blockIdx.x * 128 + wid * 32;
    int col = lane & 15, quad = lane >> 4;
    float4v acc[2][8];
#pragma unroll
    for (int rt = 0; rt < 2; rt++)
#pragma unroll
        for (int t = 0; t < 8; t++) acc[rt][t] = (float4v){0.f, 0.f, 0.f, 0.f};
    int ar[2] = {r0 + col, r0 + 16 + col};
    const float* Ap[2];
#pragma unroll
    for (int rt = 0; rt < 2; rt++) {
        int a = ar[rt];
        Ap[rt] = (a < M) ? ((a < GN) ? (A0 + (size_t)a * 128)
                                     : (A1 + (size_t)(a - GN) * 128)) : nullptr;
    }
#pragma unroll
    for (int ks = 0; ks < 4; ks++) {
        short8 af[2];
#pragma unroll
        for (int rt = 0; rt < 2; rt++) {
            af[rt] = (short8){};
            if (Ap[rt]) {
                float4 v0 = *(const float4*)&Ap[rt][ks * 32 + quad * 8];
                float4 v1 = *(const float4*)&Ap[rt][ks * 32 + quad * 8 + 4];
                af[rt][0] = (short)f2bf(v0.x); af[rt][1] = (short)f2bf(v0.y);
                af[rt][2] = (short)f2bf(v0.z); af[rt][3] = (short)f2bf(v0.w);
                af[rt][4] = (short)f2bf(v1.x); af[rt][5] = (short)f2bf(v1.y);
                af[rt][6] = (short)f2bf(v1.z); af[rt][7] = (short)f2bf(v1.w);
            }
        }
#pragma unroll
        for (int nt = 0; nt < 8; nt++) {
            short8 bf = *(const short8*)&Bs[nt * 16 + col][ks * 32 + quad * 8];
            acc[0][nt] = __builtin_amdgcn_mfma_f32_16x16x32_bf16(af[0], bf, acc[0][nt], 0, 0, 0);
            acc[1][nt] = __builtin_amdgcn_mfma_f32_16x16x32_bf16(af[1], bf, acc[1][nt], 0, 0, 0);
        }
    }
#pragma unroll
    for (int rt = 0; rt < 2; rt++)
#pragma unroll
        for (int nt = 0; nt < 8; nt++)
#pragma unroll
            for (int r = 0; r < 4; r++) {
                int row = r0 + rt * 16 + quad * 4 + r;
                if (row < M) {
                    int p = row >= GN;
                    int rr = row - (p ? GN : 0);
                    featt[ftidx(p, nt, rr, col)] = f2bf(acc[rt][nt][r]);
                }
            }
}

// ---------------- MFMA GEMM (bf16 A row-major, layer 2) ----------------
__global__ __launch_bounds__(256) void gemm_mfma(const ushort_t* __restrict__ A,
                                                 const ushort_t* __restrict__ WbT,
                                                 ushort_t* __restrict__ featt, int M) {
    __shared__ ushort_t Bs[128][136];
    int tid = threadIdx.x;
    for (int i = tid; i < 128 * 16; i += 256) {
        int n = i >> 4;
        int kc = (i & 15) << 3;
        *(short8*)&Bs[n][kc] = *(const short8*)&WbT[n * 128 + kc];
    }
    __syncthreads();
    int wid = tid >> 6, lane = tid & 63;
    int r0 = blockIdx.x * 128 + wid * 32;
    int col = lane & 15, quad = lane >> 4;
    float4v acc[2][8];
#pragma unroll
    for (int rt = 0; rt < 2; rt++)
#pragma unroll
        for (int t = 0; t < 8; t++) acc[rt][t] = (float4v){0.f, 0.f, 0.f, 0.f};
    int ar[2] = {r0 + col, r0 + 16 + col};
#pragma unroll
    for (int ks = 0; ks < 4; ks++) {
        short8 af[2];
#pragma unroll
        for (int rt = 0; rt < 2; rt++) {
            af[rt] = (short8){};
            if (ar[rt] < M) af[rt] = *(const short8*)&A[(size_t)ar[rt] * 128 + ks * 32 + quad * 8];
        }
#pragma unroll
        for (int nt = 0; nt < 8; nt++) {
            short8 bf = *(const short8*)&Bs[nt * 16 + col][ks * 32 + quad * 8];
            acc[0][nt] = __builtin_amdgcn_mfma_f32_16x16x32_bf16(af[0], bf, acc[0][nt], 0, 0, 0);
            acc[1][nt] = __builtin_amdgcn_mfma_f32_16x16x32_bf16(af[1], bf, acc[1][nt], 0, 0, 0);
        }
    }
#pragma unroll
    for (int rt = 0; rt < 2; rt++)
#pragma unroll
        for (int nt = 0; nt < 8; nt++)
#pragma unroll
            for (int r = 0; r < 4; r++) {
                int row = r0 + rt * 16 + quad * 4 + r;
                if (row < M) {
                    int p = row >= GN;
                    int rr = row - (p ? GN : 0);
                    featt[ftidx(p, nt, rr, col)] = f2bf(acc[rt][nt][r]);
                }
            }
}

// ---------------- attention logits el/er (tiled bf16 feat) ----------------
__global__ void compute_lr(const ushort_t* __restrict__ featt,
                           const float* __restrict__ al, const float* __restrict__ ar,
                           float* __restrict__ el, float* __restrict__ er, int NPH) {
    int i = blockIdx.x * 256 + threadIdx.x;   // i = p*H + h
    if (i >= NPH) return;
    int h = i & (GH - 1);
    int p = i >> 2;
    int path = p >= GN;
    int r = p - (path ? GN : 0);
    const uint_t* fA = (const uint_t*)&featt[ftidx(path, 2 * h, r, 0)];
    const uint_t* fB = (const uint_t*)&featt[ftidx(path, 2 * h + 1, r, 0)];
    const float* a = al + h * GD;
    const float* b = ar + h * GD;
    float sl = 0.f, sr = 0.f;
#pragma unroll
    for (int q = 0; q < 8; q++) {
        uint_t u = fA[q];
        float x = bflo(u), y = bfhi(u);
        sl += x * a[2 * q] + y * a[2 * q + 1];
        sr += x * b[2 * q] + y * b[2 * q + 1];
    }
#pragma unroll
    for (int q = 0; q < 8; q++) {
        uint_t u = fB[q];
        float x = bflo(u), y = bfhi(u);
        sl += x * a[16 + 2 * q] + y * a[16 + 2 * q + 1];
        sr += x * b[16 + 2 * q] + y * b[16 + 2 * q + 1];
    }
    el[i] = sl;
    er[i] = sr;
}

// ---------------- per-edge softmax weights, 1 thread = 1 edge, 4 heads ----------------
__device__ __forceinline__ uint_t pk2(float e0, float e1) {
    e0 = e0 > 0.f ? e0 : SLOPE * e0;
    e1 = e1 > 0.f ? e1 : SLOPE * e1;
    return ((uint_t)f2bf(__expf(e1)) << 16) | (uint_t)f2bf(__expf(e0));
}

__global__ void k_weights2(const int2* __restrict__ csr_sd,
                           const float* __restrict__ el, const float* __restrict__ er,
                           uint_t* __restrict__ aw, int E) {
    int j = blockIdx.x * 256 + threadIdx.x;
    if (j >= E) return;
    int2 sd = csr_sd[j];
    float4 l0 = *(const float4*)&el[(size_t)sd.x * 4];
    float4 r0 = *(const float4*)&er[(size_t)sd.y * 4];
    float4 l1 = *(const float4*)&el[((size_t)sd.x + GN) * 4];
    float4 r1 = *(const float4*)&er[((size_t)sd.y + GN) * 4];
    uint4 o;
    o.x = pk2(l0.x + r0.x, l1.x + r1.x);
    o.y = pk2(l0.y + r0.y, l1.y + r1.y);
    o.z = pk2(l0.z + r0.z, l1.z + r1.z);
    o.w = pk2(l0.w + r0.w, l1.w + r1.w);
    *(uint4*)&aw[(size_t)j * 4] = o;
}

// ---------------- aggregate: XCD-localized column tiles ----------------
// tile = blockIdx%16 -> XCD = blockIdx%8 (heuristic): XCD i only touches coltile i
// (both paths = 3.2 MB slice, L2-resident). Wave: 8 edge-slots x 8 dim-lanes.
__global__ __launch_bounds__(256) void gat_agg5(
    const ushort_t* __restrict__ featt, const uint_t* __restrict__ aw,
    const int* __restrict__ row_ptr, const int* __restrict__ csr_src,
    float* __restrict__ t0, ushort_t* __restrict__ abuf, int use_resid) {
    int tile = blockIdx.x & 15;
    int chunk = blockIdx.x >> 4;
    int path = tile >> 3, ct = tile & 7, head = ct >> 1;
    int wv = threadIdx.x >> 6, lane = threadIdx.x & 63;
    int e = lane >> 3, g = lane & 7;
    const ushort_t* fb = featt + (size_t)tile * GN * 16;
    int n0 = chunk * 16 + wv * 4;
#pragma unroll
    for (int k = 0; k < 4; k++) {
        int n = n0 + k;
        if (n >= GN) break;
        int base = row_ptr[n];
        int deg = row_ptr[n + 1] - base;
        float a0 = 0.f, a1 = 0.f, ss = 0.f;
        for (int i = 0; i < deg; i += 8) {
            bool ok = (i + e) < deg;
            int j = ok ? (base + i + e) : base;
            int s = csr_src[j];
            uint_t wp = aw[(size_t)j * 4 + head];
            float w = path ? bfhi(wp) : bflo(wp);
            if (!ok) w = 0.f;
            uint_t fv = *(const uint_t*)&fb[((size_t)s << 4) + (g << 1)];
            ss += w;
            a0 += w * bflo(fv);
            a1 += w * bfhi(fv);
        }
#pragma unroll
        for (int m = 8; m < 64; m <<= 1) {
            a0 += __shfl_xor(a0, m, 64);
            a1 += __shfl_xor(a1, m, 64);
            ss += __shfl_xor(ss, m, 64);
        }
        if (e == 0) {
            float inv = (deg > 0) ? 1.f / ss : 0.f;
            float v0 = a0 * inv, v1 = a1 * inv;
            size_t idx = ((size_t)n + (size_t)path * GN) * 128 + ct * 16 + (g << 1);
            if (use_resid) {
                float2 r = *(const float2*)&t0[idx];
                v0 += r.x;
                v1 += r.y;
            }
            v0 = v0 > 0.f ? v0 : __expf(v0) - 1.f;
            v1 = v1 > 0.f ? v1 : __expf(v1) - 1.f;
            *(float2*)&t0[idx] = make_float2(v0, v1);
            if (abuf) {
                ushort2 o;
                o.x = f2bf(v0);
                o.y = f2bf(v1);
                *(ushort2*)&abuf[idx] = o;
            }
        }
    }
}

// ---------------- mixup + output projection (Wout staged in LDS) ----------------
__global__ __launch_bounds__(256) void out_mix(const float* __restrict__ hbuf,
                                               const float* __restrict__ Wout,
                                               const float* __restrict__ bout,
                                               const float* __restrict__ lamb,
                                               float* __restrict__ outh,
                                               float* __restrict__ outlog, int Nn) {
    __shared__ float Ws[128 * 40];
    __shared__ float bs[40];
    __shared__ float hs[4][128];
    int tid = threadIdx.x;
    for (int i = tid; i < 128 * 40; i += 256) Ws[i] = Wout[i];
    if (tid < 40) bs[tid] = bout[tid];
    float lam = lamb[0];
    int w = tid >> 6, lane = tid & 63;
    __syncthreads();
    for (int node = blockIdx.x * 4 + w; node < Nn; node += 512 * 4) {
        size_t i1 = (size_t)node * 128 + (lane << 1);
        size_t i2 = (size_t)(node + GN) * 128 + (lane << 1);
        float2 a = *(const float2*)&hbuf[i1];
        float2 b = *(const float2*)&hbuf[i2];
        float m0 = lam * a.x + (1.f - lam) * b.x;
        float m1 = lam * a.y + (1.f - lam) * b.y;
        *(float2*)&outh[i1] = make_float2(m0, m1);
        hs[w][lane * 2] = m0;
        hs[w][lane * 2 + 1] = m1;
        if (lane < 40) {
            float acc = bs[lane];
#pragma unroll 4
            for (int k = 0; k < 128; k++) acc += hs[w][k] * Ws[k * 40 + lane];
            outlog[(size_t)node * 40 + lane] = acc;
        }
    }
}

extern "C" void kernel_launch(void* const* d_in, const int* in_sizes, int n_in,
                              void* d_out, int out_size, void* d_ws, size_t ws_size,
                              hipStream_t stream) {
    const float* inputs = (const float*)d_in[0];
    const float* target = (const float*)d_in[1];
    const float* lamb   = (const float*)d_in[2];
    const float* W0     = (const float*)d_in[3];
    const float* al0    = (const float*)d_in[4];
    const float* ar0    = (const float*)d_in[5];
    const float* W1     = (const float*)d_in[6];
    const float* al1    = (const float*)d_in[7];
    const float* ar1    = (const float*)d_in[8];
    const float* Wout   = (const float*)d_in[9];
    const float* bout   = (const float*)d_in[10];
    const int*   src    = (const int*)d_in[11];
    const int*   dst    = (const int*)d_in[12];

    float* out = (float*)d_out;
    float* outh = out;                          // [N,128]
    float* outlog = out + (size_t)GN * 128;     // [N,40]

    const int NP = 2 * GN;
    // workspace layout
    ushort_t* featt = (ushort_t*)d_ws;                    // [16][GN][16] bf16 tiled
    ushort_t* abuf  = featt + (size_t)NP * 128;           // [2N,128] bf16 row-major
    float* t0 = (float*)(abuf + (size_t)NP * 128);        // [2N,128] fp32
    float* el = t0 + (size_t)NP * 128;                    // [2N,4]
    float* er = el + (size_t)NP * GH;                     // [2N,4]
    uint_t* aw = (uint_t*)(er + (size_t)NP * GH);         // [E,4] bf16x2 packed
    ushort_t* wbt = (ushort_t*)(aw + (size_t)GE * 4 + 64);// [2][128][128] bf16
    int* row_ptr  = (int*)(wbt + 2 * 128 * 128);          // N+1
    int* wpos     = row_ptr + (GN + 1);                   // N
    int2* csr_sd  = (int2*)(wpos + GN);                   // E
    int* csr_src  = (int*)(csr_sd + GE + 16);             // E
    int* partials = csr_src + GE;                         // 256

    const int NPH = NP * GH;
    const int nb = (GN + 255) / 256;
    const int eb = (GE + 255) / 256;
    const int gblocks = (NP + 127) / 128;
    const int lrblocks = (NPH + 255) / 256;
    const int aggblocks = 16 * ((GN + 15) / 16);   // tile-major: blockIdx%16 = tile

    // ---- CSR build ----
    hipMemsetAsync(wpos, 0, GN * sizeof(int), stream);
    k_hist<<<eb, 256, 0, stream>>>(dst, wpos, GE);
    k_scan1<<<nb, 256, 0, stream>>>(wpos, row_ptr, partials, GN);
    k_scan2<<<1, 256, 0, stream>>>(partials, nb);
    k_scan3<<<nb, 256, 0, stream>>>(row_ptr, wpos, partials, GN, GE);
    k_fill<<<eb, 256, 0, stream>>>(src, dst, wpos, csr_sd, GE);
    k_split<<<eb, 256, 0, stream>>>(csr_sd, csr_src, GE);

    // ---- weights convert ----
    k_cvt_w<<<128, 256, 0, stream>>>(W0, W1, wbt);

    // ---- layer 1 ----
    gemm_mfma32<<<gblocks, 256, 0, stream>>>(inputs, target, wbt, featt, NP);
    compute_lr<<<lrblocks, 256, 0, stream>>>(featt, al0, ar0, el, er, NPH);
    k_weights2<<<eb, 256, 0, stream>>>(csr_sd, el, er, aw, GE);
    gat_agg5<<<aggblocks, 256, 0, stream>>>(featt, aw, row_ptr, csr_src,
                                            t0, abuf, 0);

    // ---- layer 2 ----
    gemm_mfma<<<gblocks, 256, 0, stream>>>(abuf, wbt + 128 * 128, featt, NP);
    compute_lr<<<lrblocks, 256, 0, stream>>>(featt, al1, ar1, el, er, NPH);
    k_weights2<<<eb, 256, 0, stream>>>(csr_sd, el, er, aw, GE);
    gat_agg5<<<aggblocks, 256, 0, stream>>>(featt, aw, row_ptr, csr_src,
                                            t0, nullptr, 1);

    // ---- mixup + projection ----
    out_mix<<<512, 256, 0, stream>>>(t0, Wout, bout, lamb, outh, outlog, GN);
}

// Round 7
// 479.433 us; speedup vs baseline: 1.7299x; 1.7299x over previous
//
#include <hip/hip_runtime.h>
#include <hip/hip_bf16.h>
#include <cstddef>

#define GN 50000
#define GE 800000
#define GH 4
#define GD 32
#define SLOPE 0.2f

typedef unsigned short ushort_t;
typedef unsigned int uint_t;
using short8 = __attribute__((ext_vector_type(8))) short;
using float4v = __attribute__((ext_vector_type(4))) float;

__device__ __forceinline__ ushort_t f2bf(float f) {
    union { float f; uint_t u; } v; v.f = f;
    uint_t r = v.u + 0x7fff + ((v.u >> 16) & 1);   // RNE
    return (ushort_t)(r >> 16);
}
__device__ __forceinline__ float bflo(uint_t u) { return __uint_as_float(u << 16); }
__device__ __forceinline__ float bfhi(uint_t u) { return __uint_as_float(u & 0xffff0000u); }

// ---------------- CSR build ----------------
__global__ void k_hist(const int* __restrict__ dst, int* __restrict__ deg, int E) {
    int i = blockIdx.x * 256 + threadIdx.x;
    if (i < E) atomicAdd(&deg[dst[i]], 1);
}

__global__ void k_scan1(const int* __restrict__ deg, int* __restrict__ row_ptr,
                        int* __restrict__ partials, int n) {
    __shared__ int s[256];
    int t = threadIdx.x;
    int i = blockIdx.x * 256 + t;
    int v = (i < n) ? deg[i] : 0;
    s[t] = v;
    __syncthreads();
    for (int off = 1; off < 256; off <<= 1) {
        int add = (t >= off) ? s[t - off] : 0;
        __syncthreads();
        s[t] += add;
        __syncthreads();
    }
    if (i < n) row_ptr[i] = s[t] - v;
    if (t == 255) partials[blockIdx.x] = s[255];
}

__global__ void k_scan2(int* __restrict__ partials, int nb) {
    __shared__ int s[256];
    int t = threadIdx.x;
    int v = (t < nb) ? partials[t] : 0;
    s[t] = v;
    __syncthreads();
    for (int off = 1; off < 256; off <<= 1) {
        int add = (t >= off) ? s[t - off] : 0;
        __syncthreads();
        s[t] += add;
        __syncthreads();
    }
    if (t < nb) partials[t] = s[t] - v;
}

__global__ void k_scan3(int* __restrict__ row_ptr, int* __restrict__ wpos,
                        const int* __restrict__ partials, int n, int E) {
    int i = blockIdx.x * 256 + threadIdx.x;
    if (i < n) {
        int rp = row_ptr[i] + partials[i >> 8];
        row_ptr[i] = rp;
        wpos[i] = rp;
        if (i == 0) row_ptr[n] = E;
    }
}

__global__ void k_fill(const int* __restrict__ src, const int* __restrict__ dst,
                       int* __restrict__ wpos, int2* __restrict__ csr_sd, int E) {
    int i = blockIdx.x * 256 + threadIdx.x;
    if (i < E) {
        int d = dst[i];
        int p = atomicAdd(&wpos[d], 1);
        csr_sd[p] = make_int2(src[i], d);
    }
}

// ---------------- weight transpose+convert ----------------
__global__ void k_cvt_w(const float* __restrict__ W0, const float* __restrict__ W1,
                        ushort_t* __restrict__ wbt) {
    int t = blockIdx.x * 256 + threadIdx.x;   // 0..32767
    int m = t >> 14;
    int o = t & 16383;
    int n = o >> 7, k = o & 127;
    const float* W = m ? W1 : W0;
    wbt[t] = f2bf(W[k * 128 + n]);
}

// ---- fused el/er epilogue over MFMA accumulator ----
// acc[rt][nt][r] = C[row=r0+rt*16+quad*4+r][col=nt*16+colLane]
// el[row,h] = sum_c C[row, 32h+c]*al[h,c]; butterfly over the 16 colLanes.
__device__ __forceinline__ void lr_epilogue(const float4v acc[2][8],
                                            const float* __restrict__ al,
                                            const float* __restrict__ ar,
                                            float* __restrict__ el,
                                            float* __restrict__ er,
                                            int r0, int quad, int col, int M) {
#pragma unroll
    for (int rt = 0; rt < 2; rt++) {
#pragma unroll
        for (int h = 0; h < 4; h++) {
            float alv0 = al[h * 32 + col], alv1 = al[h * 32 + 16 + col];
            float arv0 = ar[h * 32 + col], arv1 = ar[h * 32 + 16 + col];
            float pl[4], pr[4];
#pragma unroll
            for (int r = 0; r < 4; r++) {
                pl[r] = acc[rt][2 * h][r] * alv0 + acc[rt][2 * h + 1][r] * alv1;
                pr[r] = acc[rt][2 * h][r] * arv0 + acc[rt][2 * h + 1][r] * arv1;
            }
#pragma unroll
            for (int m = 1; m < 16; m <<= 1) {
#pragma unroll
                for (int r = 0; r < 4; r++) {
                    pl[r] += __shfl_xor(pl[r], m, 64);
                    pr[r] += __shfl_xor(pr[r], m, 64);
                }
            }
            if (col == h) {
#pragma unroll
                for (int r = 0; r < 4; r++) {
                    int row = r0 + rt * 16 + quad * 4 + r;
                    if (row < M) el[row * 4 + h] = pl[r];
                }
            }
            if (col == 8 + h) {
#pragma unroll
                for (int r = 0; r < 4; r++) {
                    int row = r0 + rt * 16 + quad * 4 + r;
                    if (row < M) er[row * 4 + h] = pr[r];
                }
            }
        }
    }
}

// ---------------- MFMA GEMM (fp32 A, layer 1) + fused el/er ----------------
__global__ __launch_bounds__(256) void gemm_mfma32(const float* __restrict__ A0,
                                                   const float* __restrict__ A1,
                                                   const ushort_t* __restrict__ WbT,
                                                   const float* __restrict__ al,
                                                   const float* __restrict__ ar,
                                                   ushort_t* __restrict__ Cb,
                                                   float* __restrict__ el,
                                                   float* __restrict__ er, int M) {
    __shared__ ushort_t Bs[128][136];
    int tid = threadIdx.x;
    for (int i = tid; i < 128 * 16; i += 256) {
        int n = i >> 4;
        int kc = (i & 15) << 3;
        *(short8*)&Bs[n][kc] = *(const short8*)&WbT[n * 128 + kc];
    }
    __syncthreads();
    int wid = tid >> 6, lane = tid & 63;
    int r0 = blockIdx.x * 128 + wid * 32;
    int col = lane & 15, quad = lane >> 4;
    float4v acc[2][8];
#pragma unroll
    for (int rt = 0; rt < 2; rt++)
#pragma unroll
        for (int t = 0; t < 8; t++) acc[rt][t] = (float4v){0.f, 0.f, 0.f, 0.f};
    int ar_[2] = {r0 + col, r0 + 16 + col};
    const float* Ap[2];
#pragma unroll
    for (int rt = 0; rt < 2; rt++) {
        int a = ar_[rt];
        Ap[rt] = (a < M) ? ((a < GN) ? (A0 + (size_t)a * 128)
                                     : (A1 + (size_t)(a - GN) * 128)) : nullptr;
    }
#pragma unroll
    for (int ks = 0; ks < 4; ks++) {
        short8 af[2];
#pragma unroll
        for (int rt = 0; rt < 2; rt++) {
            af[rt] = (short8){};
            if (Ap[rt]) {
                float4 v0 = *(const float4*)&Ap[rt][ks * 32 + quad * 8];
                float4 v1 = *(const float4*)&Ap[rt][ks * 32 + quad * 8 + 4];
                af[rt][0] = (short)f2bf(v0.x); af[rt][1] = (short)f2bf(v0.y);
                af[rt][2] = (short)f2bf(v0.z); af[rt][3] = (short)f2bf(v0.w);
                af[rt][4] = (short)f2bf(v1.x); af[rt][5] = (short)f2bf(v1.y);
                af[rt][6] = (short)f2bf(v1.z); af[rt][7] = (short)f2bf(v1.w);
            }
        }
#pragma unroll
        for (int nt = 0; nt < 8; nt++) {
            short8 bf = *(const short8*)&Bs[nt * 16 + col][ks * 32 + quad * 8];
            acc[0][nt] = __builtin_amdgcn_mfma_f32_16x16x32_bf16(af[0], bf, acc[0][nt], 0, 0, 0);
            acc[1][nt] = __builtin_amdgcn_mfma_f32_16x16x32_bf16(af[1], bf, acc[1][nt], 0, 0, 0);
        }
    }
#pragma unroll
    for (int rt = 0; rt < 2; rt++)
#pragma unroll
        for (int nt = 0; nt < 8; nt++)
#pragma unroll
            for (int r = 0; r < 4; r++) {
                int row = r0 + rt * 16 + quad * 4 + r;
                if (row < M) Cb[(size_t)row * 128 + nt * 16 + col] = f2bf(acc[rt][nt][r]);
            }
    lr_epilogue(acc, al, ar, el, er, r0, quad, col, M);
}

// ---------------- MFMA GEMM (bf16 A, layer 2) + fused el/er ----------------
__global__ __launch_bounds__(256) void gemm_mfma(const ushort_t* __restrict__ A,
                                                 const ushort_t* __restrict__ WbT,
                                                 const float* __restrict__ al,
                                                 const float* __restrict__ ar,
                                                 ushort_t* __restrict__ Cb,
                                                 float* __restrict__ el,
                                                 float* __restrict__ er, int M) {
    __shared__ ushort_t Bs[128][136];
    int tid = threadIdx.x;
    for (int i = tid; i < 128 * 16; i += 256) {
        int n = i >> 4;
        int kc = (i & 15) << 3;
        *(short8*)&Bs[n][kc] = *(const short8*)&WbT[n * 128 + kc];
    }
    __syncthreads();
    int wid = tid >> 6, lane = tid & 63;
    int r0 = blockIdx.x * 128 + wid * 32;
    int col = lane & 15, quad = lane >> 4;
    float4v acc[2][8];
#pragma unroll
    for (int rt = 0; rt < 2; rt++)
#pragma unroll
        for (int t = 0; t < 8; t++) acc[rt][t] = (float4v){0.f, 0.f, 0.f, 0.f};
    int ar_[2] = {r0 + col, r0 + 16 + col};
#pragma unroll
    for (int ks = 0; ks < 4; ks++) {
        short8 af[2];
#pragma unroll
        for (int rt = 0; rt < 2; rt++) {
            af[rt] = (short8){};
            if (ar_[rt] < M) af[rt] = *(const short8*)&A[(size_t)ar_[rt] * 128 + ks * 32 + quad * 8];
        }
#pragma unroll
        for (int nt = 0; nt < 8; nt++) {
            short8 bf = *(const short8*)&Bs[nt * 16 + col][ks * 32 + quad * 8];
            acc[0][nt] = __builtin_amdgcn_mfma_f32_16x16x32_bf16(af[0], bf, acc[0][nt], 0, 0, 0);
            acc[1][nt] = __builtin_amdgcn_mfma_f32_16x16x32_bf16(af[1], bf, acc[1][nt], 0, 0, 0);
        }
    }
#pragma unroll
    for (int rt = 0; rt < 2; rt++)
#pragma unroll
        for (int nt = 0; nt < 8; nt++)
#pragma unroll
            for (int r = 0; r < 4; r++) {
                int row = r0 + rt * 16 + quad * 4 + r;
                if (row < M) Cb[(size_t)row * 128 + nt * 16 + col] = f2bf(acc[rt][nt][r]);
            }
    lr_epilogue(acc, al, ar, el, er, r0, quad, col, M);
}

// ---------------- per-edge softmax weights, 1 thread = 1 edge, 4 heads ----------------
__device__ __forceinline__ uint_t pk2(float e0, float e1) {
    e0 = e0 > 0.f ? e0 : SLOPE * e0;
    e1 = e1 > 0.f ? e1 : SLOPE * e1;
    return ((uint_t)f2bf(__expf(e1)) << 16) | (uint_t)f2bf(__expf(e0));
}

__global__ void k_weights2(const int2* __restrict__ csr_sd,
                           const float* __restrict__ el, const float* __restrict__ er,
                           uint_t* __restrict__ aw, int E) {
    int j = blockIdx.x * 256 + threadIdx.x;
    if (j >= E) return;
    int2 sd = csr_sd[j];
    float4 l0 = *(const float4*)&el[(size_t)sd.x * 4];
    float4 r0 = *(const float4*)&er[(size_t)sd.y * 4];
    float4 l1 = *(const float4*)&el[((size_t)sd.x + GN) * 4];
    float4 r1 = *(const float4*)&er[((size_t)sd.y + GN) * 4];
    uint4 o;
    o.x = pk2(l0.x + r0.x, l1.x + r1.x);
    o.y = pk2(l0.y + r0.y, l1.y + r1.y);
    o.z = pk2(l0.z + r0.z, l1.z + r1.z);
    o.w = pk2(l0.w + r0.w, l1.w + r1.w);
    *(uint4*)&aw[(size_t)j * 4] = o;
}

// ---------------- aggregate: one wave per node; lanes 0-31 path0, 32-63 path1 ----------------
// lane q=lane&31 owns dims 4q..4q+3 (uint2 gather, 8 B); head = q>>3.
// csr addresses are wave-uniform -> scalar loads; aw direct per-lane load.
__global__ __launch_bounds__(256) void gat_agg7(
    const ushort_t* __restrict__ featb, const uint_t* __restrict__ aw,
    const int* __restrict__ row_ptr, const int2* __restrict__ csr_sd,
    float* __restrict__ io, ushort_t* __restrict__ iob, int use_resid) {
    int n = blockIdx.x * 4 + (threadIdx.x >> 6);
    if (n >= GN) return;
    int lane = threadIdx.x & 63;
    int half = lane >> 5;
    int q = lane & 31;
    int head = q >> 3;
    int q4 = q << 2;
    const ushort_t* fb = featb + half * (GN * 128);
    int base = row_ptr[n];
    int deg = row_ptr[n + 1] - base;

    float a0 = 0.f, a1 = 0.f, a2 = 0.f, a3 = 0.f, ss = 0.f;
    int i = 0;
    for (; i + 8 <= deg; i += 8) {
        int j = base + i;
        int s0 = csr_sd[j + 0].x, s1 = csr_sd[j + 1].x, s2 = csr_sd[j + 2].x, s3 = csr_sd[j + 3].x;
        int s4 = csr_sd[j + 4].x, s5 = csr_sd[j + 5].x, s6 = csr_sd[j + 6].x, s7 = csr_sd[j + 7].x;
        uint_t p0 = aw[(j + 0) * 4 + head], p1 = aw[(j + 1) * 4 + head];
        uint_t p2 = aw[(j + 2) * 4 + head], p3 = aw[(j + 3) * 4 + head];
        uint_t p4 = aw[(j + 4) * 4 + head], p5 = aw[(j + 5) * 4 + head];
        uint_t p6 = aw[(j + 6) * 4 + head], p7 = aw[(j + 7) * 4 + head];
        uint2 f0 = *(const uint2*)&fb[s0 * 128 + q4];
        uint2 f1 = *(const uint2*)&fb[s1 * 128 + q4];
        uint2 f2 = *(const uint2*)&fb[s2 * 128 + q4];
        uint2 f3 = *(const uint2*)&fb[s3 * 128 + q4];
        uint2 f4 = *(const uint2*)&fb[s4 * 128 + q4];
        uint2 f5 = *(const uint2*)&fb[s5 * 128 + q4];
        uint2 f6 = *(const uint2*)&fb[s6 * 128 + q4];
        uint2 f7 = *(const uint2*)&fb[s7 * 128 + q4];
        float w0 = half ? bfhi(p0) : bflo(p0);
        float w1 = half ? bfhi(p1) : bflo(p1);
        float w2 = half ? bfhi(p2) : bflo(p2);
        float w3 = half ? bfhi(p3) : bflo(p3);
        float w4 = half ? bfhi(p4) : bflo(p4);
        float w5 = half ? bfhi(p5) : bflo(p5);
        float w6 = half ? bfhi(p6) : bflo(p6);
        float w7 = half ? bfhi(p7) : bflo(p7);
        ss += ((w0 + w1) + (w2 + w3)) + ((w4 + w5) + (w6 + w7));
        a0 += w0 * bflo(f0.x) + w1 * bflo(f1.x) + w2 * bflo(f2.x) + w3 * bflo(f3.x) +
              w4 * bflo(f4.x) + w5 * bflo(f5.x) + w6 * bflo(f6.x) + w7 * bflo(f7.x);
        a1 += w0 * bfhi(f0.x) + w1 * bfhi(f1.x) + w2 * bfhi(f2.x) + w3 * bfhi(f3.x) +
              w4 * bfhi(f4.x) + w5 * bfhi(f5.x) + w6 * bfhi(f6.x) + w7 * bfhi(f7.x);
        a2 += w0 * bflo(f0.y) + w1 * bflo(f1.y) + w2 * bflo(f2.y) + w3 * bflo(f3.y) +
              w4 * bflo(f4.y) + w5 * bflo(f5.y) + w6 * bflo(f6.y) + w7 * bflo(f7.y);
        a3 += w0 * bfhi(f0.y) + w1 * bfhi(f1.y) + w2 * bfhi(f2.y) + w3 * bfhi(f3.y) +
              w4 * bfhi(f4.y) + w5 * bfhi(f5.y) + w6 * bfhi(f6.y) + w7 * bfhi(f7.y);
    }
    for (; i < deg; i++) {
        int j = base + i;
        int s = csr_sd[j].x;
        uint_t p = aw[j * 4 + head];
        uint2 f = *(const uint2*)&fb[s * 128 + q4];
        float w = half ? bfhi(p) : bflo(p);
        ss += w;
        a0 += w * bflo(f.x);
        a1 += w * bfhi(f.x);
        a2 += w * bflo(f.y);
        a3 += w * bfhi(f.y);
    }
    float inv = (deg > 0) ? 1.f / ss : 0.f;
    float v0 = a0 * inv, v1 = a1 * inv, v2 = a2 * inv, v3 = a3 * inv;
    size_t idx = ((size_t)n + (size_t)half * GN) * 128 + q4;
    if (use_resid) {
        float4 r = *(const float4*)&io[idx];
        v0 += r.x; v1 += r.y; v2 += r.z; v3 += r.w;
    }
    v0 = v0 > 0.f ? v0 : __expf(v0) - 1.f;
    v1 = v1 > 0.f ? v1 : __expf(v1) - 1.f;
    v2 = v2 > 0.f ? v2 : __expf(v2) - 1.f;
    v3 = v3 > 0.f ? v3 : __expf(v3) - 1.f;
    *(float4*)&io[idx] = make_float4(v0, v1, v2, v3);
    if (iob) {
        ushort4 o;
        o.x = f2bf(v0); o.y = f2bf(v1); o.z = f2bf(v2); o.w = f2bf(v3);
        *(ushort4*)&iob[idx] = o;
    }
}

// ---------------- mixup + output projection (Wout staged in LDS) ----------------
__global__ __launch_bounds__(256) void out_mix(const float* __restrict__ hbuf,
                                               const float* __restrict__ Wout,
                                               const float* __restrict__ bout,
                                               const float* __restrict__ lamb,
                                               float* __restrict__ outh,
                                               float* __restrict__ outlog, int Nn) {
    __shared__ float Ws[128 * 40];
    __shared__ float bs[40];
    __shared__ float hs[4][128];
    int tid = threadIdx.x;
    for (int i = tid; i < 128 * 40; i += 256) Ws[i] = Wout[i];
    if (tid < 40) bs[tid] = bout[tid];
    float lam = lamb[0];
    int w = tid >> 6, lane = tid & 63;
    __syncthreads();
    for (int node = blockIdx.x * 4 + w; node < Nn; node += 512 * 4) {
        size_t i1 = (size_t)node * 128 + (lane << 1);
        size_t i2 = (size_t)(node + GN) * 128 + (lane << 1);
        float2 a = *(const float2*)&hbuf[i1];
        float2 b = *(const float2*)&hbuf[i2];
        float m0 = lam * a.x + (1.f - lam) * b.x;
        float m1 = lam * a.y + (1.f - lam) * b.y;
        *(float2*)&outh[i1] = make_float2(m0, m1);
        hs[w][lane * 2] = m0;
        hs[w][lane * 2 + 1] = m1;
        if (lane < 40) {
            float acc = bs[lane];
#pragma unroll 4
            for (int k = 0; k < 128; k++) acc += hs[w][k] * Ws[k * 40 + lane];
            outlog[(size_t)node * 40 + lane] = acc;
        }
    }
}

extern "C" void kernel_launch(void* const* d_in, const int* in_sizes, int n_in,
                              void* d_out, int out_size, void* d_ws, size_t ws_size,
                              hipStream_t stream) {
    const float* inputs = (const float*)d_in[0];
    const float* target = (const float*)d_in[1];
    const float* lamb   = (const float*)d_in[2];
    const float* W0     = (const float*)d_in[3];
    const float* al0    = (const float*)d_in[4];
    const float* ar0    = (const float*)d_in[5];
    const float* W1     = (const float*)d_in[6];
    const float* al1    = (const float*)d_in[7];
    const float* ar1    = (const float*)d_in[8];
    const float* Wout   = (const float*)d_in[9];
    const float* bout   = (const float*)d_in[10];
    const int*   src    = (const int*)d_in[11];
    const int*   dst    = (const int*)d_in[12];

    float* out = (float*)d_out;
    float* outh = out;                          // [N,128]
    float* outlog = out + (size_t)GN * 128;     // [N,40]

    const int NP = 2 * GN;
    // workspace layout
    ushort_t* featb = (ushort_t*)d_ws;                    // [2N,128] bf16
    ushort_t* abuf  = featb + (size_t)NP * 128;           // [2N,128] bf16 (layer1 agg out)
    float* t0 = (float*)(abuf + (size_t)NP * 128);        // [2N,128] fp32
    float* el = t0 + (size_t)NP * 128;                    // [2N,4]
    float* er = el + (size_t)NP * GH;                     // [2N,4]
    uint_t* aw = (uint_t*)(er + (size_t)NP * GH);         // [E,4] bf16x2 packed
    ushort_t* wbt = (ushort_t*)(aw + (size_t)GE * 4 + 64);// [2][128][128] bf16
    int* row_ptr  = (int*)(wbt + 2 * 128 * 128);          // N+1
    int* wpos     = row_ptr + (GN + 1);                   // N
    int2* csr_sd  = (int2*)(wpos + GN);                   // E (+pad)
    int* partials = (int*)(csr_sd + GE + 16);             // 256

    const int nb = (GN + 255) / 256;
    const int eb = (GE + 255) / 256;
    const int gblocks = (NP + 127) / 128;
    const int aggblocks = (GN + 3) / 4;

    // ---- CSR build ----
    hipMemsetAsync(wpos, 0, GN * sizeof(int), stream);
    k_hist<<<eb, 256, 0, stream>>>(dst, wpos, GE);
    k_scan1<<<nb, 256, 0, stream>>>(wpos, row_ptr, partials, GN);
    k_scan2<<<1, 256, 0, stream>>>(partials, nb);
    k_scan3<<<nb, 256, 0, stream>>>(row_ptr, wpos, partials, GN, GE);
    k_fill<<<eb, 256, 0, stream>>>(src, dst, wpos, csr_sd, GE);

    // ---- weights convert ----
    k_cvt_w<<<128, 256, 0, stream>>>(W0, W1, wbt);

    // ---- layer 1 (GEMM fuses el/er) ----
    gemm_mfma32<<<gblocks, 256, 0, stream>>>(inputs, target, wbt, al0, ar0,
                                             featb, el, er, NP);
    k_weights2<<<eb, 256, 0, stream>>>(csr_sd, el, er, aw, GE);
    gat_agg7<<<aggblocks, 256, 0, stream>>>(featb, aw, row_ptr, csr_sd,
                                            t0, abuf, 0);

    // ---- layer 2 ----
    gemm_mfma<<<gblocks, 256, 0, stream>>>(abuf, wbt + 128 * 128, al1, ar1,
                                           featb, el, er, NP);
    k_weights2<<<eb, 256, 0, stream>>>(csr_sd, el, er, aw, GE);
    gat_agg7<<<aggblocks, 256, 0, stream>>>(featb, aw, row_ptr, csr_sd,
                                            t0, nullptr, 1);

    // ---- mixup + projection ----
    out_mix<<<512, 256, 0, stream>>>(t0, Wout, bout, lamb, outh, outlog, GN);
}